// Round 3
// baseline (382.047 us; speedup 1.0000x reference)
//
#include <hip/hip_runtime.h>
#include <hip/hip_bf16.h>
#include <math.h>

// Problem constants
#define B_ 8
#define S_ 4096
#define E_ 1024
#define H_ 128
#define MIN_K 32
// d_out layout: filtered [B,S,E] | selection_mask [B,S] | expected_k [B]
#define OUT_MASK_OFF (B_*S_*E_)
#define OUT_EK_OFF   (B_*S_*E_ + B_*S_)

// workspace byte offsets (total 917,536 B)
#define LOGITS_OFF 0
#define SOFT_OFF   131072
#define CNT_OFF    262144
#define KROW_OFF   393216
#define W1T_HI_OFF 393248   // 16B aligned
#define W1T_LO_OFF 655392   // 16B aligned

typedef __attribute__((ext_vector_type(8))) short   frag8;   // 8 bf16 (4 VGPR)
typedef __attribute__((ext_vector_type(4))) float   fragc;   // 4 f32 acc

static __device__ __forceinline__ unsigned short bf16_rne(float f) {
  unsigned u = __float_as_uint(f);
  unsigned r = u + 0x7FFF + ((u >> 16) & 1);
  return (unsigned short)(r >> 16);
}
static __device__ __forceinline__ float bf16_to_f32(unsigned short h) {
  return __uint_as_float(((unsigned)h) << 16);
}

// ---------------------------------------------------------------------------
// Prep: w1 [E][H] f32  ->  w1t_hi/w1t_lo [H][E] bf16 (transposed, k-contiguous)
// ---------------------------------------------------------------------------
__global__ __launch_bounds__(256) void prep_w_kernel(
    const float* __restrict__ w1,
    unsigned short* __restrict__ w1t_hi, unsigned short* __restrict__ w1t_lo)
{
  int id = blockIdx.x * 256 + threadIdx.x;       // 0..32767
  int k  = id >> 5;                               // 0..1023
  int n4 = id & 31;                               // 0..31
  float4 w = *(const float4*)(w1 + k * H_ + n4 * 4);
#pragma unroll
  for (int e = 0; e < 4; ++e) {
    float f = (e == 0) ? w.x : (e == 1) ? w.y : (e == 2) ? w.z : w.w;
    unsigned short hi = bf16_rne(f);
    unsigned short lo = bf16_rne(f - bf16_to_f32(hi));
    int n = n4 * 4 + e;
    w1t_hi[n * E_ + k] = hi;
    w1t_lo[n * E_ + k] = lo;
  }
}

// ---------------------------------------------------------------------------
// Scorer v3: LDS-free, barrier-free K-loop.
// v1/v2 post-mortem: barrier-locked staging pays full memory latency per
// K-step (~5800 cyc/step, all pipes <12% busy). The vmcnt(0) drain at every
// __syncthreads is structural (m97 pathology). Fix: each lane loads its own
// MFMA A-fragment (8 contiguous f32 of one x-row) direct from global and
// converts to split-bf16 in-register. No LDS staging, no per-step barriers;
// compiler emits counted vmcnt for depth-1 prefetched A/B register buffers.
// Tiling: wave = 32 m (2 mt) x 64 n (4 nt); block = 4 waves = 64 m x 128 n.
// Grid 512, 8 waves/CU (2/SIMD), ~180 VGPR.
// Logit reduction replicates v1's tree exactly -> logits bitwise identical.
// ---------------------------------------------------------------------------
#define KT 32
#define NTILES (E_ / KT)

__global__ __launch_bounds__(256, 2) void scorer_kernel(
    const float* __restrict__ x,
    const unsigned short* __restrict__ w1t_hi,
    const unsigned short* __restrict__ w1t_lo,
    const float* __restrict__ b1, const float* __restrict__ w2,
    const float* __restrict__ b2, float* __restrict__ logits)
{
  __shared__ float part[2][4][32];   // [m-half][g0..g3][row-within-32]

  const int tid  = threadIdx.x;
  const int wv   = tid >> 6;
  const int lane = tid & 63;
  const int l15  = lane & 15;
  const int quad = lane >> 4;
  const int mh   = wv >> 1;          // m-half: rows [mh*32, mh*32+32)
  const int nh   = wv & 1;           // n-half: cols [nh*64, nh*64+64)
  const int m0   = blockIdx.x * 64;

  // per-lane A row pointers (row = m0 + mh*32 + mt*16 + l15, col base quad*8)
  const float* __restrict__ ar[2];
#pragma unroll
  for (int mt = 0; mt < 2; ++mt)
    ar[mt] = x + (size_t)(m0 + mh * 32 + mt * 16 + l15) * E_ + quad * 8;

  // per-lane B row pointers (row n = nh*64 + nt*16 + l15, col base quad*8)
  const unsigned short* __restrict__ bhp[4];
  const unsigned short* __restrict__ blp[4];
#pragma unroll
  for (int nt = 0; nt < 4; ++nt) {
    size_t off = (size_t)(nh * 64 + nt * 16 + l15) * E_ + quad * 8;
    bhp[nt] = w1t_hi + off;
    blp[nt] = w1t_lo + off;
  }

  fragc acc[2][4];
#pragma unroll
  for (int mt = 0; mt < 2; ++mt)
#pragma unroll
    for (int nt = 0; nt < 4; ++nt)
      acc[mt][nt] = (fragc)(0.f);

  // double-buffered register prefetch (A raw f32, B frags)
  float4 Ax[2][2][2];   // [buf][mt][half]
  frag8  Bh[2][4], Bl[2][4];

  // prologue: buf 0 <- k-tile 0
#pragma unroll
  for (int mt = 0; mt < 2; ++mt) {
    Ax[0][mt][0] = *(const float4*)(ar[mt] + 0);
    Ax[0][mt][1] = *(const float4*)(ar[mt] + 4);
  }
#pragma unroll
  for (int nt = 0; nt < 4; ++nt) {
    Bh[0][nt] = *(const frag8*)(bhp[nt]);
    Bl[0][nt] = *(const frag8*)(blp[nt]);
  }

#pragma unroll 2
  for (int t = 0; t < NTILES; ++t) {
    const int cur = t & 1;
    const int nxt = cur ^ 1;
    const int kn = (t + 1 < NTILES) ? (t + 1) * KT : 0;  // clamped (values unused at t=31)

    // issue prefetch for tile t+1 (long-latency first: A from x)
#pragma unroll
    for (int mt = 0; mt < 2; ++mt) {
      Ax[nxt][mt][0] = *(const float4*)(ar[mt] + kn);
      Ax[nxt][mt][1] = *(const float4*)(ar[mt] + kn + 4);
    }
#pragma unroll
    for (int nt = 0; nt < 4; ++nt) {
      Bh[nxt][nt] = *(const frag8*)(bhp[nt] + kn);
      Bl[nxt][nt] = *(const frag8*)(blp[nt] + kn);
    }

    // convert A[cur] to split-bf16 frags (bitwise same values as v1 staging)
    frag8 ah[2], al[2];
#pragma unroll
    for (int mt = 0; mt < 2; ++mt) {
      float f[8] = {Ax[cur][mt][0].x, Ax[cur][mt][0].y, Ax[cur][mt][0].z, Ax[cur][mt][0].w,
                    Ax[cur][mt][1].x, Ax[cur][mt][1].y, Ax[cur][mt][1].z, Ax[cur][mt][1].w};
#pragma unroll
      for (int e = 0; e < 8; ++e) {
        unsigned short hi = bf16_rne(f[e]);
        ah[mt][e] = (short)hi;
        al[mt][e] = (short)bf16_rne(f[e] - bf16_to_f32(hi));
      }
    }

    // 24 MFMAs; per-acc chain order identical to v1: hh, hl, lh
#pragma unroll
    for (int mt = 0; mt < 2; ++mt)
#pragma unroll
      for (int nt = 0; nt < 4; ++nt) {
        acc[mt][nt] = __builtin_amdgcn_mfma_f32_16x16x32_bf16(ah[mt], Bh[cur][nt], acc[mt][nt], 0, 0, 0);
        acc[mt][nt] = __builtin_amdgcn_mfma_f32_16x16x32_bf16(ah[mt], Bl[cur][nt], acc[mt][nt], 0, 0, 0);
        acc[mt][nt] = __builtin_amdgcn_mfma_f32_16x16x32_bf16(al[mt], Bh[cur][nt], acc[mt][nt], 0, 0, 0);
      }
  }

  // Epilogue. v1-order reduction: per 32-n group, in-register fma over its
  // 2 n-tiles, then 16-lane butterfly; final ((g0+g1)+(g2+g3)).
  float b1v[4], w2v[4];
#pragma unroll
  for (int nt = 0; nt < 4; ++nt) {
    int n = nh * 64 + nt * 16 + l15;
    b1v[nt] = b1[n]; w2v[nt] = w2[n];
  }
  float pA[2][4], pB[2][4];   // [mt][reg]: n-subgroups (nt 0,1) and (nt 2,3)
#pragma unroll
  for (int mt = 0; mt < 2; ++mt)
#pragma unroll
    for (int reg = 0; reg < 4; ++reg) {
      float p = 0.f;
#pragma unroll
      for (int nt = 0; nt < 2; ++nt) {
        float h = acc[mt][nt][reg] + b1v[nt];
        h = h > 0.f ? h : 0.f;
        p = fmaf(h, w2v[nt], p);
      }
      pA[mt][reg] = p;
      p = 0.f;
#pragma unroll
      for (int nt = 2; nt < 4; ++nt) {
        float h = acc[mt][nt][reg] + b1v[nt];
        h = h > 0.f ? h : 0.f;
        p = fmaf(h, w2v[nt], p);
      }
      pB[mt][reg] = p;
    }
#pragma unroll
  for (int mask = 1; mask < 16; mask <<= 1)
#pragma unroll
    for (int mt = 0; mt < 2; ++mt)
#pragma unroll
      for (int reg = 0; reg < 4; ++reg) {
        pA[mt][reg] += __shfl_xor(pA[mt][reg], mask);
        pB[mt][reg] += __shfl_xor(pB[mt][reg], mask);
      }

  if (l15 == 0) {
#pragma unroll
    for (int mt = 0; mt < 2; ++mt)
#pragma unroll
      for (int reg = 0; reg < 4; ++reg) {
        int rl = mt * 16 + quad * 4 + reg;
        part[mh][nh * 2 + 0][rl] = pA[mt][reg];
        part[mh][nh * 2 + 1][rl] = pB[mt][reg];
      }
  }
  __syncthreads();
  if (tid < 64) {
    int rmh = tid >> 5, rl = tid & 31;
    logits[m0 + tid] = ((part[rmh][0][rl] + part[rmh][1][rl]) +
                        (part[rmh][2][rl] + part[rmh][3][rl])) + b2[0];
  }
}

// ---------------------------------------------------------------------------
// Row kernel: expected_k, k, gumbel, softmax. grid=8, block=1024. (unchanged)
// ---------------------------------------------------------------------------
__global__ __launch_bounds__(1024) void row_kernel(
    const float* __restrict__ logits, const float* __restrict__ u,
    float* __restrict__ soft, int* __restrict__ krow, float* __restrict__ ek_out)
{
  const int b = blockIdx.x;
  const int t = threadIdx.x;
  const float* Lrow = logits + b * S_;
  const float* urow = u + b * S_;

  __shared__ double red[1024];
  __shared__ float  redf[1024];

  float z[4];
  double psig = 0.0;
  float zmax = -INFINITY;
#pragma unroll
  for (int i = 0; i < 4; ++i) {
    int j = t + i * 1024;
    float L = Lrow[j];
    float g = -logf(-logf(urow[j]));
    z[i] = L + g;
    psig += (double)(1.f / (1.f + expf(-L)));
    zmax = fmaxf(zmax, z[i]);
  }
  red[t] = psig; redf[t] = zmax;
  __syncthreads();
  for (int s2 = 512; s2 > 0; s2 >>= 1) {
    if (t < s2) { red[t] += red[t + s2]; redf[t] = fmaxf(redf[t], redf[t + s2]); }
    __syncthreads();
  }
  __shared__ float m_sh; __shared__ double ek_sh;
  if (t == 0) { m_sh = redf[0]; ek_sh = red[0]; }
  __syncthreads();
  float m = m_sh;

  float e[4];
  double pexp = 0.0;
#pragma unroll
  for (int i = 0; i < 4; ++i) { e[i] = expf(z[i] - m); pexp += (double)e[i]; }
  red[t] = pexp;
  __syncthreads();
  for (int s2 = 512; s2 > 0; s2 >>= 1) {
    if (t < s2) red[t] += red[t + s2];
    __syncthreads();
  }
  __shared__ float den_sh;
  if (t == 0) den_sh = (float)red[0];
  __syncthreads();
  float den = den_sh;
#pragma unroll
  for (int i = 0; i < 4; ++i) soft[b * S_ + t + i * 1024] = e[i] / den;

  if (t == 0) {
    float ekf = (float)ek_sh;
    int k = (int)ekf;
    if (k < MIN_K) k = MIN_K;
    krow[b] = k;
    ek_out[b] = ekf;
  }
}

// ---------------------------------------------------------------------------
// Rank partial: grid (16 i-chunks, 4 j-chunks, 8 rows). Integer atomicAdd
// (deterministic). j-chunk staged in LDS; all lanes read same addr (broadcast).
// ---------------------------------------------------------------------------
__global__ __launch_bounds__(256) void rank_kernel(
    const float* __restrict__ soft, int* __restrict__ counts)
{
  __shared__ float4 sjs[256];
  const int b  = blockIdx.z;
  const int ic = blockIdx.x;
  const int jc = blockIdx.y;
  const int tid = threadIdx.x;
  const float* row = soft + b * S_;

  sjs[tid] = ((const float4*)row)[jc * 256 + tid];
  const int i = ic * 256 + tid;
  const float si = row[i];
  __syncthreads();

  int cnt = 0;
  const int jbase = jc * 1024;
  for (int j4 = 0; j4 < 256; ++j4) {
    float4 vv = sjs[j4];
    int j = jbase + j4 * 4;
    cnt += (vv.x > si) || (vv.x == si && (j + 0) < i);
    cnt += (vv.y > si) || (vv.y == si && (j + 1) < i);
    cnt += (vv.z > si) || (vv.z == si && (j + 2) < i);
    cnt += (vv.w > si) || (vv.w == si && (j + 3) < i);
  }
  atomicAdd(&counts[b * S_ + i], cnt);
}

// ---------------------------------------------------------------------------
// Filter + mask finalize: one block per token (1024 floats). Uniform scalar
// loads of cnt/k/soft; thread 0 writes selection_mask.
// ---------------------------------------------------------------------------
__global__ __launch_bounds__(256) void filter_kernel(
    const float* __restrict__ x, const float* __restrict__ soft,
    const int* __restrict__ counts, const int* __restrict__ krow,
    float* __restrict__ out, float* __restrict__ mask_out)
{
  const int token = blockIdx.x;           // 0..32767
  const int b = token >> 12;              // S_=4096
  const float s = soft[token];
  const float h = (counts[token] < krow[b]) ? 1.f : 0.f;
  const float sel = (h - s) + s;

  size_t base = (size_t)token * (E_ / 4) + threadIdx.x;
  float4 v = ((const float4*)x)[base];
  v.x *= sel; v.y *= sel; v.z *= sel; v.w *= sel;
  ((float4*)out)[base] = v;
  if (threadIdx.x == 0) mask_out[token] = sel;
}

// ---------------------------------------------------------------------------
extern "C" void kernel_launch(void* const* d_in, const int* in_sizes, int n_in,
                              void* d_out, int out_size, void* d_ws, size_t ws_size,
                              hipStream_t stream) {
  const float* x  = (const float*)d_in[0];
  const float* w1 = (const float*)d_in[1];
  const float* b1 = (const float*)d_in[2];
  const float* w2 = (const float*)d_in[3];
  const float* b2 = (const float*)d_in[4];
  const float* u  = (const float*)d_in[5];

  float* out = (float*)d_out;
  float* out_filt = out;
  float* out_mask = out + OUT_MASK_OFF;
  float* out_ek   = out + OUT_EK_OFF;

  char* ws = (char*)d_ws;
  float*          ws_logits = (float*)(ws + LOGITS_OFF);
  float*          ws_soft   = (float*)(ws + SOFT_OFF);
  int*            ws_cnt    = (int*)(ws + CNT_OFF);
  int*            ws_krow   = (int*)(ws + KROW_OFF);
  unsigned short* ws_w1thi  = (unsigned short*)(ws + W1T_HI_OFF);
  unsigned short* ws_w1tlo  = (unsigned short*)(ws + W1T_LO_OFF);

  hipMemsetAsync(ws_cnt, 0, B_ * S_ * sizeof(int), stream);
  prep_w_kernel<<<dim3(128), dim3(256), 0, stream>>>(w1, ws_w1thi, ws_w1tlo);
  scorer_kernel<<<dim3(B_ * S_ / 64), dim3(256), 0, stream>>>(
      x, ws_w1thi, ws_w1tlo, b1, w2, b2, ws_logits);
  row_kernel<<<dim3(B_), dim3(1024), 0, stream>>>(ws_logits, u, ws_soft, ws_krow, out_ek);
  rank_kernel<<<dim3(16, 4, 8), dim3(256), 0, stream>>>(ws_soft, ws_cnt);
  filter_kernel<<<dim3(B_ * S_), dim3(256), 0, stream>>>(
      x, ws_soft, ws_cnt, ws_krow, out_filt, out_mask);
}